// Round 7
// baseline (520.858 us; speedup 1.0000x reference)
//
#include <hip/hip_runtime.h>
#include <math.h>

typedef unsigned short ushort_t;
typedef unsigned int uint_t;

#define NIMG 12        // B*N
#define NCH  256       // FC
#define FH   32
#define FW   88
#define NPIX 2816      // FH*FW
#define NDEP 20        // depth bins: 1,4,...,58
#define NOUTC 128
#define NVOX 65536     // 256*256
#define NPTS 675840    // NIMG*NDEP*NPIX
#define NKEY 131072    // 2*NVOX
#define BEV_FLOATS 16777216u  // 2*128*65536

// ---- workspace layout (BYTE offsets), total 90099712 ----
#define B_MATS   0u          // 1152
#define B_A1     4096u
#define B_C1     5120u
#define B_A2     6144u
#define B_C2     7168u
#define B_TOT    278528u     // 4
#define B_FEAT   282624u     // bf16 feat: 33792*128*2 = 8650752
#define B_RECS   17584128u   // 5406720 -> 22990848
#define B_BEV    22990848u   // 67108864 -> 90099712 (the "hole")
// inside hole (all dead before bevtmp memset):
#define B_VCODE  22990848u   // 2703360
#define B_WT     25694208u   // 2703360
#define B_CNT    28397568u   // 524288
#define B_OFFS   28921856u   // 524288
#define B_CUR    29446144u   // 524288
#define B_SPINE  29970432u   // 2048
#define B_XBF    29972480u   // 17301504
#define B_ACT1   47273984u   // 17301504
#define B_ACT2   64575488u   // 17301504
#define B_WSWZ1  81876992u   // single-bf16: 9*8*16*512*2 = 1179648
#define B_WSWZ2  83056640u   // 1179648
#define B_WSWZ3  84236288u   // split hi/lo: 8*9*2*512*2 = 147456

typedef __attribute__((ext_vector_type(8))) short bf16x8;
typedef __attribute__((ext_vector_type(4))) float floatx4;
typedef __attribute__((ext_vector_type(4))) uint_t u32x4;

__device__ __forceinline__ ushort_t f2bf(float f) {
    uint_t x = __float_as_uint(f);
    return (ushort_t)((x + 0x7fffu + ((x >> 16) & 1u)) >> 16);
}
__device__ __forceinline__ float bf2f(ushort_t u) {
    return __uint_as_float(((uint_t)u) << 16);
}

__device__ __forceinline__ void inv3x3(const float* __restrict__ M, float* __restrict__ o) {
    float a=M[0],b=M[1],c=M[2],d=M[3],e=M[4],f=M[5],g=M[6],h=M[7],i=M[8];
    float A = e*i - f*h;
    float B = c*h - b*i;
    float C = b*f - c*e;
    float D = f*g - d*i;
    float E = a*i - c*g;
    float F = c*d - a*f;
    float G = d*h - e*g;
    float H = b*g - a*h;
    float I = a*e - b*d;
    float det = a*A + b*D + c*G;
    float id = 1.0f / det;
    o[0]=A*id; o[1]=B*id; o[2]=C*id;
    o[3]=D*id; o[4]=E*id; o[5]=F*id;
    o[6]=G*id; o[7]=H*id; o[8]=I*id;
}

// ---- weight swizzle into MFMA A-fragment order ----
__device__ __forceinline__ void wprep_one(
    const float* __restrict__ w, ushort_t* __restrict__ dst,
    int ntap, int ncib, int ncog, int nco, int nci, int idx, bool split)
{
    int j = idx & 7;
    int l = (idx >> 3) & 63;
    int pairidx = idx >> 9;
    int g = pairidx % ncog;
    int b = (pairidx / ncog) % ncib;
    int t = pairidx / (ncog * ncib);
    int co = g * 16 + (l & 15);
    int ci = b * 32 + (l >> 4) * 8 + j;
    float v = 0.0f;
    if (co < nco) v = w[((size_t)co * nci + ci) * ntap + t];
    ushort_t hi = f2bf(v);
    if (split) {
        dst[(size_t)pairidx * 1024 + l * 8 + j]       = hi;
        dst[(size_t)pairidx * 1024 + 512 + l * 8 + j] = f2bf(v - bf2f(hi));
    } else {
        dst[(size_t)pairidx * 512 + l * 8 + j] = hi;
    }
}

// ---- fused: weight swizzle (all 3 convs) + per-(b,n) matrices + BN folding ----
__global__ __launch_bounds__(256) void wprep_all_kernel(
    const float* __restrict__ w1, ushort_t* __restrict__ d1,
    const float* __restrict__ w2, ushort_t* __restrict__ d2,
    const float* __restrict__ w3, ushort_t* __restrict__ d3,
    const float* __restrict__ c2e_rot, const float* __restrict__ c2e_trans,
    const float* __restrict__ intrins, const float* __restrict__ post_rot,
    const float* __restrict__ post_trans,
    const float* __restrict__ c1b, const float* __restrict__ s1,
    const float* __restrict__ bb1, const float* __restrict__ m1, const float* __restrict__ v1,
    const float* __restrict__ c2b, const float* __restrict__ s2,
    const float* __restrict__ bb2, const float* __restrict__ m2, const float* __restrict__ v2,
    float* __restrict__ mats, float* __restrict__ A1, float* __restrict__ C1,
    float* __restrict__ A2, float* __restrict__ C2)
{
    int bid = blockIdx.x;
    int t = threadIdx.x;
    if (bid < 2304) {
        wprep_one(w1, d1, 9, 8, 16, 256, 256, bid * 256 + t, false);
    } else if (bid < 4608) {
        wprep_one(w2, d2, 9, 8, 16, 256, 256, (bid - 2304) * 256 + t, false);
    } else if (bid < 4752) {
        int idx = (bid - 4608) * 256 + t;
        if (idx < 36864) wprep_one(w3, d3, 1, 8, 9, 130, 256, idx, true);
    } else {
        // prep: matrices + BN fold
        if (t < NIMG) {
            float ip[9], ki[9], comb[9];
            inv3x3(post_rot + t*9, ip);
            inv3x3(intrins  + t*9, ki);
            const float* R = c2e_rot + t*9;
            #pragma unroll
            for (int r = 0; r < 3; ++r)
                #pragma unroll
                for (int c = 0; c < 3; ++c)
                    comb[r*3+c] = R[r*3+0]*ki[0*3+c] + R[r*3+1]*ki[1*3+c] + R[r*3+2]*ki[2*3+c];
            float* M = mats + t*24;
            #pragma unroll
            for (int k = 0; k < 9; ++k) { M[k] = ip[k]; M[9+k] = comb[k]; }
            M[18] = c2e_trans[t*3+0]; M[19] = c2e_trans[t*3+1]; M[20] = c2e_trans[t*3+2];
            M[21] = post_trans[t*3+0]; M[22] = post_trans[t*3+1]; M[23] = post_trans[t*3+2];
        }
        float i1 = s1[t] / sqrtf(v1[t] + 1e-3f);
        A1[t] = i1;
        C1[t] = (c1b[t] - m1[t]) * i1 + bb1[t];
        float i2 = s2[t] / sqrtf(v2[t] + 1e-3f);
        A2[t] = i2;
        C2[t] = (c2b[t] - m2[t]) * i2 + bb2[t];
    }
}

// ---- voxel code per frustum point + fused histogram (run-length aggregated) ----
__global__ __launch_bounds__(256) void geom_kernel(
    const float* __restrict__ mats, int* __restrict__ vcode, uint_t* __restrict__ cnt)
{
    int i = blockIdx.x * 256 + threadIdx.x;
    int lane = threadIdx.x & 63;
    int hw  = i % NPIX;
    int tmp = i / NPIX;
    int d   = tmp % NDEP;
    int bn  = tmp / NDEP;
    int h = hw / FW, w = hw - h * FW;
    const float* M = mats + bn * 24;
    float xs = (float)w * (703.0f / 87.0f);
    float ys = (float)h * (255.0f / 31.0f);
    float dv = 1.0f + 3.0f * (float)d;
    float fx = xs - M[21], fy = ys - M[22], fz = dv - M[23];
    float p0 = M[0]*fx + M[1]*fy + M[2]*fz;
    float p1 = M[3]*fx + M[4]*fy + M[5]*fz;
    float p2 = M[6]*fx + M[7]*fy + M[8]*fz;
    p0 *= p2; p1 *= p2;
    float gx = M[ 9]*p0 + M[10]*p1 + M[11]*p2 + M[18];
    float gy = M[12]*p0 + M[13]*p1 + M[14]*p2 + M[19];
    float gz = M[15]*p0 + M[16]*p1 + M[17]*p2 + M[20];
    const float cx = -51.0f - 0.2f, cy = -51.0f - 0.2f, cz = 0.0f - 10.0f;
    int ix = (int)((gx - cx) / 0.4f);
    int iy = (int)((gy - cy) / 0.4f);
    int iz = (int)((gz - cz) / 20.0f);
    bool kept = (ix >= 0) && (ix < 256) && (iy >= 0) && (iy < 256) && (iz == 0);
    int code = kept ? ((ix << 8) | iy) : -1;
    vcode[i] = code;

    int b = bn / 6;
    uint_t key = kept ? (uint_t)((b << 16) | code) : 0xFFFFFFFFu;
    uint_t prevkey = __shfl_up(key, 1);
    bool leader = (lane == 0) || (key != prevkey);
    unsigned long long mask = __ballot(leader);
    if (leader && kept) {
        unsigned long long higher = mask & ~((2ULL << lane) - 1ULL);
        int nxt = higher ? (__ffsll((long long)higher) - 1) : 64;
        atomicAdd(&cnt[key], (uint_t)(nxt - lane));
    }
}

// ---- cast + transpose img_feats fp32 [img][ci][px] -> bf16 [img*px][ci] ----
__global__ __launch_bounds__(256) void cast_transpose_kernel(
    const float* __restrict__ in, ushort_t* __restrict__ out)
{
    __shared__ __align__(16) ushort_t lds[64 * 264];
    int img = blockIdx.y;
    int px0 = blockIdx.x * 64;
    int t = threadIdx.x;
    const float* src = in + (size_t)img * NCH * NPIX;
    int pxl = t & 63;
    int cib = t >> 6;
    #pragma unroll 4
    for (int cc = 0; cc < 64; ++cc) {
        int ci = cc * 4 + cib;
        float v = src[(size_t)ci * NPIX + px0 + pxl];
        lds[pxl * 264 + ci] = f2bf(v);
    }
    __syncthreads();
    int wv = t >> 6, lane = t & 63;
    uint2* outv = (uint2*)out;
    #pragma unroll
    for (int i = 0; i < 16; ++i) {
        int p = wv * 16 + i;
        uint2 val = *(const uint2*)&lds[p * 264 + lane * 4];
        outv[(size_t)(img * NPIX + px0 + p) * 64 + lane] = val;
    }
}

// ---- 3x3 conv + BN + ReLU via bf16 MFMA ----
// grid (img*32 rows, 2 co-groups of 128), block 128 (2 waves).
// wave w owns 64 co (4 m-tiles) -> 1 LDS b-read feeds 4 MFMAs.
// LDS 16B-chunk slot XOR-swizzled with (col>>1)&3 -> conflict-free reads.
__global__ __launch_bounds__(128) void conv3x3_mfma(
    const ushort_t* __restrict__ in,     // [img*2816][256] bf16
    const ushort_t* __restrict__ wswz,   // [9][8][16][64][8] bf16 (single)
    const float* __restrict__ Abn, const float* __restrict__ Cbn,
    ushort_t* __restrict__ out)          // [img*2816][256] bf16
{
    __shared__ __align__(16) ushort_t lds[2][8640];
    int bx = blockIdx.x;            // img*32 + h
    int cg = blockIdx.y;
    int img = bx >> 5, h = bx & 31;
    int t = threadIdx.x;            // 0..127
    int w = t >> 6, l = t & 63;
    int q = l >> 4, c = l & 15;
    const int n0s[6] = {0, 16, 32, 48, 64, 72};

    // zero both buffers once (halo + out-of-range rows stay zero forever)
    for (int i = t; i < 8640; i += 128) ((uint_t*)lds)[i] = 0;

    const u32x4* src4 = (const u32x4*)(in + (size_t)img * NPIX * 256);
    const bf16x8* wsA = (const bf16x8*)wswz;

    // staging geometry: 1056 16B-chunks over 128 threads -> 9 per thread
    int gbase[9], loff[9];
    bool sval[9];
    #pragma unroll
    for (int k = 0; k < 9; ++k) {
        int p = t + k * 128;
        bool valid = (p < 1056);
        int chunk = p >> 2, sub = p & 3;
        int r = chunk / 88;
        int col = chunk - r * 88;
        int hin = h - 1 + r;
        bool inb = valid && (hin >= 0) && (hin < FH);
        sval[k] = inb;
        gbase[k] = inb ? ((hin * 88 + col) * 32 + sub) : 0;
        int cs = col + 1;                         // stored column
        int slot = sub ^ ((cs >> 1) & 3);         // bank swizzle
        loff[k] = ((r * 90 + cs) * 4 + slot) * 8;
    }

    floatx4 acc[4][6];
    #pragma unroll
    for (int m = 0; m < 4; ++m)
        #pragma unroll
        for (int n = 0; n < 6; ++n)
            acc[m][n] = (floatx4){0.f, 0.f, 0.f, 0.f};

    int g0 = cg * 8 + w * 4;

    __syncthreads();                 // zeros visible
    #pragma unroll
    for (int k = 0; k < 9; ++k)
        if (sval[k]) *(u32x4*)&lds[0][loff[k]] = src4[gbase[k]];

    int buf = 0;
    for (int kb = 0; kb < 8; ++kb) {
        __syncthreads();
        u32x4 sreg[9];
        if (kb < 7) {
            #pragma unroll
            for (int k = 0; k < 9; ++k)
                if (sval[k]) sreg[k] = src4[gbase[k] + (kb + 1) * 4];
        }
        const bf16x8* B = (const bf16x8*)lds[buf];

        #pragma unroll
        for (int t9 = 0; t9 < 9; ++t9) {
            int pa = (t9 * 8 + kb) * 16;
            bf16x8 a0 = wsA[(size_t)(pa + g0    ) * 64 + l];
            bf16x8 a1 = wsA[(size_t)(pa + g0 + 1) * 64 + l];
            bf16x8 a2 = wsA[(size_t)(pa + g0 + 2) * 64 + l];
            bf16x8 a3 = wsA[(size_t)(pa + g0 + 3) * 64 + l];
            int ky = t9 / 3, kx = t9 - ky * 3;
            #pragma unroll
            for (int n = 0; n < 6; ++n) {
                int col = n0s[n] + kx + c;        // stored column
                int slot = q ^ ((col >> 1) & 3);
                bf16x8 b = B[(ky * 90 + col) * 4 + slot];
                acc[0][n] = __builtin_amdgcn_mfma_f32_16x16x32_bf16(a0, b, acc[0][n], 0, 0, 0);
                acc[1][n] = __builtin_amdgcn_mfma_f32_16x16x32_bf16(a1, b, acc[1][n], 0, 0, 0);
                acc[2][n] = __builtin_amdgcn_mfma_f32_16x16x32_bf16(a2, b, acc[2][n], 0, 0, 0);
                acc[3][n] = __builtin_amdgcn_mfma_f32_16x16x32_bf16(a3, b, acc[3][n], 0, 0, 0);
            }
        }
        if (kb < 7) {
            #pragma unroll
            for (int k = 0; k < 9; ++k)
                if (sval[k]) *(u32x4*)&lds[buf ^ 1][loff[k]] = sreg[k];
        }
        buf ^= 1;
    }

    // epilogue: BN + ReLU, store bf16 channel-last
    #pragma unroll
    for (int m = 0; m < 4; ++m) {
        int cob = cg * 128 + w * 64 + m * 16 + q * 4;
        float ba0 = Abn[cob+0], ba1 = Abn[cob+1], ba2 = Abn[cob+2], ba3 = Abn[cob+3];
        float bc0 = Cbn[cob+0], bc1 = Cbn[cob+1], bc2 = Cbn[cob+2], bc3 = Cbn[cob+3];
        #pragma unroll
        for (int n = 0; n < 6; ++n) {
            if (n == 5 && c < 8) continue;
            int col = n0s[n] + c;
            floatx4 v = acc[m][n];
            uint_t lo = (uint_t)f2bf(fmaxf(v[0]*ba0+bc0, 0.f)) | ((uint_t)f2bf(fmaxf(v[1]*ba1+bc1, 0.f)) << 16);
            uint_t hi = (uint_t)f2bf(fmaxf(v[2]*ba2+bc2, 0.f)) | ((uint_t)f2bf(fmaxf(v[3]*ba3+bc3, 0.f)) << 16);
            uint2 val; val.x = lo; val.y = hi;
            *(uint2*)&out[((size_t)img * NPIX + h * 88 + col) * 256 + cob] = val;
        }
    }
}

// ---- 1x1 conv 256->130 via MFMA (split-bf16 weights) + fused gaussian weights ----
__global__ __launch_bounds__(256, 4) void gemm1x1_mfma(
    const ushort_t* __restrict__ act2,
    const ushort_t* __restrict__ wswz3,
    const float* __restrict__ b3,
    ushort_t* __restrict__ feat, float* __restrict__ wt)
{
    int t = threadIdx.x, wv = t >> 6, l = t & 63, q = l >> 4, c = l & 15;
    int n0 = (blockIdx.x * 4 + wv) * 16;
    int px = n0 + c;
    const bf16x8* A = (const bf16x8*)wswz3;
    const bf16x8* B = (const bf16x8*)act2;
    floatx4 acc[9];
    #pragma unroll
    for (int g = 0; g < 9; ++g) acc[g] = (floatx4){0.f, 0.f, 0.f, 0.f};
    for (int kb = 0; kb < 8; ++kb) {
        bf16x8 b = B[(size_t)px * 32 + kb * 4 + q];
        #pragma unroll
        for (int g = 0; g < 9; ++g) {
            size_t pa = (size_t)(kb * 9 + g) * 128;
            acc[g] = __builtin_amdgcn_mfma_f32_16x16x32_bf16(A[pa + l],      b, acc[g], 0, 0, 0);
            acc[g] = __builtin_amdgcn_mfma_f32_16x16x32_bf16(A[pa + 64 + l], b, acc[g], 0, 0, 0);
        }
    }
    // feat store (co 2..129)
    #pragma unroll
    for (int g = 0; g < 9; ++g) {
        #pragma unroll
        for (int r = 0; r < 4; ++r) {
            int co = g * 16 + q * 4 + r;
            if (co < 2 || co >= 130) continue;
            feat[(size_t)px * 128 + (co - 2)] = f2bf(acc[g][r] + b3[co]);
        }
    }
    // fused gaussian depth weights: mu=co0, log_sigma=co1 live on lanes 0..15
    float muv = acc[0][0] + b3[0];
    float lsv = acc[0][1] + b3[1];
    float mu_b  = __shfl(muv, c);               // broadcast from lane c (q==0)
    float sig   = expf(__shfl(lsv, c)) + 1e-6f;
    float ninv2 = -0.5f / (sig * sig);
    float g5[5]; float s = 0.0f;
    #pragma unroll
    for (int j = 0; j < 5; ++j) {
        float dv = 1.0f + 3.0f * (float)(q * 5 + j);
        float df = dv - mu_b;
        g5[j] = expf(df * df * ninv2);
        s += g5[j];
    }
    s += __shfl_xor(s, 16);
    s += __shfl_xor(s, 32);
    float inv = 1.0f / (s + 1e-6f);
    #pragma unroll
    for (int j = 0; j < 5; ++j)
        wt[(size_t)px * NDEP + q * 5 + j] = g5[j] * inv;
}

// ---- block-level exclusive scan (spine holds raw block sums) ----
__global__ __launch_bounds__(256) void scan_block_kernel(
    const uint_t* __restrict__ cnt, uint_t* __restrict__ offs, uint_t* __restrict__ spine)
{
    __shared__ uint_t s[256];
    int t = threadIdx.x;
    int i = blockIdx.x * 256 + t;
    uint_t v = cnt[i];
    s[t] = v;
    __syncthreads();
    #pragma unroll
    for (int off = 1; off < 256; off <<= 1) {
        uint_t add = (t >= off) ? s[t - off] : 0u;
        __syncthreads();
        s[t] += add;
        __syncthreads();
    }
    offs[i] = s[t] - v;
    if (t == 255) spine[blockIdx.x] = s[255];
}

// ---- fixup: per-block spine prefix (recomputed), offsets, cursor, mask, total ----
__global__ __launch_bounds__(256) void fixup_kernel(
    uint_t* __restrict__ offs, const uint_t* __restrict__ spine,
    uint_t* __restrict__ cursor, const uint_t* __restrict__ cnt,
    float* __restrict__ mask_out, uint_t* __restrict__ total)
{
    __shared__ uint_t red[256];
    int bid = blockIdx.x, t = threadIdx.x;
    uint_t part = 0;
    for (int j = t; j < bid; j += 256) part += spine[j];
    red[t] = part;
    __syncthreads();
    #pragma unroll
    for (int off = 128; off > 0; off >>= 1) {
        if (t < off) red[t] += red[t + off];
        __syncthreads();
    }
    uint_t prefix = red[0];
    int i = bid * 256 + t;
    uint_t o = offs[i] + prefix;
    offs[i] = o;
    cursor[i] = o;
    uint_t n = cnt[i];
    mask_out[i] = (n > 0) ? 1.0f : 0.0f;
    if (i == NKEY - 1) *total = o + n;
}

// ---- scatter with run-length aggregated cursor atomics ----
__global__ __launch_bounds__(256) void scatter_kernel(
    const int* __restrict__ vcode, const float* __restrict__ wt,
    uint_t* __restrict__ cursor, uint2* __restrict__ recs)
{
    int i = blockIdx.x * 256 + threadIdx.x;
    int lane = threadIdx.x & 63;
    int code = vcode[i];
    int hw  = i % NPIX;
    int tmp = i / NPIX;
    int d   = tmp % NDEP;
    int bn  = tmp / NDEP;
    int b   = bn / 6;
    int gp  = bn * NPIX + hw;           // < 33792, fits 16 bits
    bool active = (code >= 0);
    uint_t key = active ? (uint_t)((b << 16) | code) : 0xFFFFFFFFu;
    uint2 r;
    r.x = ((uint_t)(code & 0xffff) << 16) | (uint_t)gp;
    r.y = active ? __float_as_uint(wt[(size_t)gp * NDEP + d]) : 0u;

    uint_t prevkey = __shfl_up(key, 1);
    bool leader = (lane == 0) || (key != prevkey);
    unsigned long long mask = __ballot(leader);
    uint_t base = 0;
    if (leader && active) {
        unsigned long long higher = mask & ~((2ULL << lane) - 1ULL);
        int nxt = higher ? (__ffsll((long long)higher) - 1) : 64;
        base = atomicAdd(&cursor[key], (uint_t)(nxt - lane));
    }
    unsigned long long lower = mask & ((2ULL << lane) - 1ULL);
    int lead = 63 - __clzll((long long)lower);   // lower nonzero (lane0 is leader)
    base = __shfl(base, lead);
    if (active) recs[base + (lane - lead)] = r;
}

// ---- segmented reduce: one wave per 64-record chunk; feat is bf16 ----
__global__ __launch_bounds__(256) void segreduce_kernel(
    const uint2* __restrict__ recs, const uint_t* __restrict__ total,
    const uint_t* __restrict__ featu,   // [33792][64] dwords (bf16x2)
    float* __restrict__ bev_tmp)
{
    uint_t R = *total;
    int wid = blockIdx.x * 4 + (threadIdx.x >> 6);
    uint_t start = (uint_t)wid * 64u;
    if (start >= R) return;
    int lane = threadIdx.x & 63;
    uint_t ustart = __builtin_amdgcn_readfirstlane(start);

    uint2 r0 = recs[ustart];
    uint_t gp0 = r0.x & 0xffffu;
    uint_t prevk = ((gp0 >= 16896u) ? 0x10000u : 0u) | (r0.x >> 16);
    float acc0 = 0.f, acc1 = 0.f;

    #pragma unroll 8
    for (int e = 0; e < 64; ++e) {
        uint2 re = recs[ustart + e];
        uint_t gp = re.x & 0xffffu;
        uint_t key = ((gp >= 16896u) ? 0x10000u : 0u) | (re.x >> 16);
        float wv = __uint_as_float(re.y);
        if (ustart + e >= R) { key = prevk; wv = 0.f; gp = 0u; }  // uniform
        if (key != prevk) {                                        // uniform
            float* p = bev_tmp + (size_t)prevk * NOUTC;
            atomicAdd(p + 2 * lane,     acc0);
            atomicAdd(p + 2 * lane + 1, acc1);
            acc0 = acc1 = 0.f;
            prevk = key;
        }
        uint_t fv = featu[(size_t)gp * 64 + lane];
        acc0 = fmaf(wv, bf2f((ushort_t)(fv & 0xffffu)), acc0);
        acc1 = fmaf(wv, bf2f((ushort_t)(fv >> 16)),     acc1);
    }
    float* p = bev_tmp + (size_t)prevk * NOUTC;
    atomicAdd(p + 2 * lane,     acc0);
    atomicAdd(p + 2 * lane + 1, acc1);
}

// ---- channel-last -> channel-first BEV transpose ----
__global__ __launch_bounds__(256) void transpose_kernel(
    const float* __restrict__ bev_tmp, float* __restrict__ bev_out)
{
    __shared__ float lds[64 * 129];
    int blk = blockIdx.x;              // 0..2047
    int b   = blk >> 10;
    int v0  = (blk & 1023) * 64;
    int t   = threadIdx.x;
    const float* src = bev_tmp + ((size_t)b * NVOX + v0) * NOUTC;
    #pragma unroll
    for (int k = 0; k < 32; ++k) {
        int idx = k * 256 + t;
        int v = idx >> 7, ch = idx & 127;
        lds[v * 129 + ch] = src[idx];
    }
    __syncthreads();
    float* dst = bev_out + (size_t)b * NOUTC * NVOX + v0;
    #pragma unroll
    for (int k = 0; k < 32; ++k) {
        int idx = k * 256 + t;
        int vl = idx & 63, ch = idx >> 6;
        dst[(size_t)ch * NVOX + vl] = lds[vl * 129 + ch];
    }
}

extern "C" void kernel_launch(void* const* d_in, const int* in_sizes, int n_in,
                              void* d_out, int out_size, void* d_ws, size_t ws_size,
                              hipStream_t stream) {
    const float* c2e_rot    = (const float*)d_in[0];
    const float* c2e_trans  = (const float*)d_in[1];
    const float* intrins    = (const float*)d_in[2];
    const float* post_rot   = (const float*)d_in[3];
    const float* post_trans = (const float*)d_in[4];
    const float* img_feats  = (const float*)d_in[5];
    const float* conv1_w    = (const float*)d_in[6];
    const float* conv1_b    = (const float*)d_in[7];
    const float* bn1_s = (const float*)d_in[8];
    const float* bn1_b = (const float*)d_in[9];
    const float* bn1_m = (const float*)d_in[10];
    const float* bn1_v = (const float*)d_in[11];
    const float* conv2_w = (const float*)d_in[12];
    const float* conv2_b = (const float*)d_in[13];
    const float* bn2_s = (const float*)d_in[14];
    const float* bn2_b = (const float*)d_in[15];
    const float* bn2_m = (const float*)d_in[16];
    const float* bn2_v = (const float*)d_in[17];
    const float* conv3_w = (const float*)d_in[18];
    const float* conv3_b = (const float*)d_in[19];

    char* base = (char*)d_ws;
    float*    mats   = (float*)(base + B_MATS);
    float*    A1     = (float*)(base + B_A1);
    float*    C1     = (float*)(base + B_C1);
    float*    A2     = (float*)(base + B_A2);
    float*    C2     = (float*)(base + B_C2);
    uint_t*   total  = (uint_t*)(base + B_TOT);
    ushort_t* feat   = (ushort_t*)(base + B_FEAT);
    uint2*    recs   = (uint2*)(base + B_RECS);
    float*    bevtmp = (float*)(base + B_BEV);
    int*      vcode  = (int*)(base + B_VCODE);
    float*    wt     = (float*)(base + B_WT);
    uint_t*   cnt    = (uint_t*)(base + B_CNT);
    uint_t*   offs   = (uint_t*)(base + B_OFFS);
    uint_t*   cursor = (uint_t*)(base + B_CUR);
    uint_t*   spine  = (uint_t*)(base + B_SPINE);
    ushort_t* xbf    = (ushort_t*)(base + B_XBF);
    ushort_t* act1   = (ushort_t*)(base + B_ACT1);
    ushort_t* act2   = (ushort_t*)(base + B_ACT2);
    ushort_t* wswz1  = (ushort_t*)(base + B_WSWZ1);
    ushort_t* wswz2  = (ushort_t*)(base + B_WSWZ2);
    ushort_t* wswz3  = (ushort_t*)(base + B_WSWZ3);

    float* bev_out  = (float*)d_out;
    float* mask_out = bev_out + BEV_FLOATS;

    hipMemsetAsync(cnt, 0, NKEY * sizeof(uint_t), stream);
    wprep_all_kernel<<<4753, 256, 0, stream>>>(conv1_w, wswz1, conv2_w, wswz2, conv3_w, wswz3,
                                               c2e_rot, c2e_trans, intrins, post_rot, post_trans,
                                               conv1_b, bn1_s, bn1_b, bn1_m, bn1_v,
                                               conv2_b, bn2_s, bn2_b, bn2_m, bn2_v,
                                               mats, A1, C1, A2, C2);
    geom_kernel<<<NPTS / 256, 256, 0, stream>>>(mats, vcode, cnt);
    cast_transpose_kernel<<<dim3(44, 12), 256, 0, stream>>>(img_feats, xbf);
    conv3x3_mfma<<<dim3(NIMG * 32, 2), 128, 0, stream>>>(xbf,  wswz1, A1, C1, act1);
    conv3x3_mfma<<<dim3(NIMG * 32, 2), 128, 0, stream>>>(act1, wswz2, A2, C2, act2);
    gemm1x1_mfma<<<528, 256, 0, stream>>>(act2, wswz3, conv3_b, feat, wt);
    scan_block_kernel<<<NKEY / 256, 256, 0, stream>>>(cnt, offs, spine);
    fixup_kernel<<<NKEY / 256, 256, 0, stream>>>(offs, spine, cursor, cnt, mask_out, total);
    scatter_kernel<<<NPTS / 256, 256, 0, stream>>>(vcode, wt, cursor, recs);
    // all hole-resident buffers now dead
    hipMemsetAsync(bevtmp, 0, (size_t)BEV_FLOATS * sizeof(float), stream);
    segreduce_kernel<<<(NPTS / 64 + 3) / 4, 256, 0, stream>>>(recs, total, (const uint_t*)feat, bevtmp);
    transpose_kernel<<<2048, 256, 0, stream>>>(bevtmp, bev_out);
}

// Round 8
// 380.432 us; speedup vs baseline: 1.3691x; 1.3691x over previous
//
#include <hip/hip_runtime.h>
#include <math.h>

typedef unsigned short ushort_t;
typedef unsigned int uint_t;

#define NIMG 12        // B*N
#define NCH  256       // FC
#define FH   32
#define FW   88
#define NPIX 2816      // FH*FW
#define NDEP 20        // depth bins: 1,4,...,58
#define NOUTC 128
#define NVOX 65536     // 256*256
#define NPTS 675840    // NIMG*NDEP*NPIX
#define NKEY 131072    // 2*NVOX
#define BEV_FLOATS 16777216u  // 2*128*65536

// ---- workspace layout (BYTE offsets), total 90099712 ----
#define B_MATS   0u          // 1152
#define B_A1     4096u
#define B_C1     5120u
#define B_A2     6144u
#define B_C2     7168u
#define B_TOT    278528u     // 4
#define B_FEAT   282624u     // bf16 feat: 33792*128*2 = 8650752
#define B_RECS   17584128u   // 5406720 -> 22990848
#define B_BEV    22990848u   // 67108864 -> 90099712 (the "hole")
// inside hole (all dead before bevtmp memset):
#define B_VCODE  22990848u   // 2703360
#define B_WT     25694208u   // 2703360
#define B_CNT    28397568u   // 524288
#define B_OFFS   28921856u   // 524288
#define B_CUR    29446144u   // 524288
#define B_SPINE  29970432u   // 2048
#define B_XBF    29972480u   // 17301504
#define B_ACT1   47273984u   // 17301504
#define B_ACT2   64575488u   // 17301504
#define B_WSWZ1  81876992u   // single-bf16: 9*8*16*512*2 = 1179648
#define B_WSWZ2  83056640u   // 1179648
#define B_WSWZ3  84236288u   // split hi/lo: 8*9*2*512*2 = 147456

typedef __attribute__((ext_vector_type(8))) short bf16x8;
typedef __attribute__((ext_vector_type(4))) float floatx4;
typedef __attribute__((ext_vector_type(4))) uint_t u32x4;

__device__ __forceinline__ ushort_t f2bf(float f) {
    uint_t x = __float_as_uint(f);
    return (ushort_t)((x + 0x7fffu + ((x >> 16) & 1u)) >> 16);
}
__device__ __forceinline__ float bf2f(ushort_t u) {
    return __uint_as_float(((uint_t)u) << 16);
}

__device__ __forceinline__ void inv3x3(const float* __restrict__ M, float* __restrict__ o) {
    float a=M[0],b=M[1],c=M[2],d=M[3],e=M[4],f=M[5],g=M[6],h=M[7],i=M[8];
    float A = e*i - f*h;
    float B = c*h - b*i;
    float C = b*f - c*e;
    float D = f*g - d*i;
    float E = a*i - c*g;
    float F = c*d - a*f;
    float G = d*h - e*g;
    float H = b*g - a*h;
    float I = a*e - b*d;
    float det = a*A + b*D + c*G;
    float id = 1.0f / det;
    o[0]=A*id; o[1]=B*id; o[2]=C*id;
    o[3]=D*id; o[4]=E*id; o[5]=F*id;
    o[6]=G*id; o[7]=H*id; o[8]=I*id;
}

// ---- weight swizzle into MFMA A-fragment order ----
__device__ __forceinline__ void wprep_one(
    const float* __restrict__ w, ushort_t* __restrict__ dst,
    int ntap, int ncib, int ncog, int nco, int nci, int idx, bool split)
{
    int j = idx & 7;
    int l = (idx >> 3) & 63;
    int pairidx = idx >> 9;
    int g = pairidx % ncog;
    int b = (pairidx / ncog) % ncib;
    int t = pairidx / (ncog * ncib);
    int co = g * 16 + (l & 15);
    int ci = b * 32 + (l >> 4) * 8 + j;
    float v = 0.0f;
    if (co < nco) v = w[((size_t)co * nci + ci) * ntap + t];
    ushort_t hi = f2bf(v);
    if (split) {
        dst[(size_t)pairidx * 1024 + l * 8 + j]       = hi;
        dst[(size_t)pairidx * 1024 + 512 + l * 8 + j] = f2bf(v - bf2f(hi));
    } else {
        dst[(size_t)pairidx * 512 + l * 8 + j] = hi;
    }
}

// ---- fused: weight swizzle (all 3 convs) + per-(b,n) matrices + BN folding ----
__global__ __launch_bounds__(256) void wprep_all_kernel(
    const float* __restrict__ w1, ushort_t* __restrict__ d1,
    const float* __restrict__ w2, ushort_t* __restrict__ d2,
    const float* __restrict__ w3, ushort_t* __restrict__ d3,
    const float* __restrict__ c2e_rot, const float* __restrict__ c2e_trans,
    const float* __restrict__ intrins, const float* __restrict__ post_rot,
    const float* __restrict__ post_trans,
    const float* __restrict__ c1b, const float* __restrict__ s1,
    const float* __restrict__ bb1, const float* __restrict__ m1, const float* __restrict__ v1,
    const float* __restrict__ c2b, const float* __restrict__ s2,
    const float* __restrict__ bb2, const float* __restrict__ m2, const float* __restrict__ v2,
    float* __restrict__ mats, float* __restrict__ A1, float* __restrict__ C1,
    float* __restrict__ A2, float* __restrict__ C2)
{
    int bid = blockIdx.x;
    int t = threadIdx.x;
    if (bid < 2304) {
        wprep_one(w1, d1, 9, 8, 16, 256, 256, bid * 256 + t, false);
    } else if (bid < 4608) {
        wprep_one(w2, d2, 9, 8, 16, 256, 256, (bid - 2304) * 256 + t, false);
    } else if (bid < 4752) {
        int idx = (bid - 4608) * 256 + t;
        if (idx < 36864) wprep_one(w3, d3, 1, 8, 9, 130, 256, idx, true);
    } else {
        // prep: matrices + BN fold
        if (t < NIMG) {
            float ip[9], ki[9], comb[9];
            inv3x3(post_rot + t*9, ip);
            inv3x3(intrins  + t*9, ki);
            const float* R = c2e_rot + t*9;
            #pragma unroll
            for (int r = 0; r < 3; ++r)
                #pragma unroll
                for (int c = 0; c < 3; ++c)
                    comb[r*3+c] = R[r*3+0]*ki[0*3+c] + R[r*3+1]*ki[1*3+c] + R[r*3+2]*ki[2*3+c];
            float* M = mats + t*24;
            #pragma unroll
            for (int k = 0; k < 9; ++k) { M[k] = ip[k]; M[9+k] = comb[k]; }
            M[18] = c2e_trans[t*3+0]; M[19] = c2e_trans[t*3+1]; M[20] = c2e_trans[t*3+2];
            M[21] = post_trans[t*3+0]; M[22] = post_trans[t*3+1]; M[23] = post_trans[t*3+2];
        }
        float i1 = s1[t] / sqrtf(v1[t] + 1e-3f);
        A1[t] = i1;
        C1[t] = (c1b[t] - m1[t]) * i1 + bb1[t];
        float i2 = s2[t] / sqrtf(v2[t] + 1e-3f);
        A2[t] = i2;
        C2[t] = (c2b[t] - m2[t]) * i2 + bb2[t];
    }
}

// ---- voxel code per frustum point + fused histogram (run-length aggregated) ----
__global__ __launch_bounds__(256) void geom_kernel(
    const float* __restrict__ mats, int* __restrict__ vcode, uint_t* __restrict__ cnt)
{
    int i = blockIdx.x * 256 + threadIdx.x;
    int lane = threadIdx.x & 63;
    int hw  = i % NPIX;
    int tmp = i / NPIX;
    int d   = tmp % NDEP;
    int bn  = tmp / NDEP;
    int h = hw / FW, w = hw - h * FW;
    const float* M = mats + bn * 24;
    float xs = (float)w * (703.0f / 87.0f);
    float ys = (float)h * (255.0f / 31.0f);
    float dv = 1.0f + 3.0f * (float)d;
    float fx = xs - M[21], fy = ys - M[22], fz = dv - M[23];
    float p0 = M[0]*fx + M[1]*fy + M[2]*fz;
    float p1 = M[3]*fx + M[4]*fy + M[5]*fz;
    float p2 = M[6]*fx + M[7]*fy + M[8]*fz;
    p0 *= p2; p1 *= p2;
    float gx = M[ 9]*p0 + M[10]*p1 + M[11]*p2 + M[18];
    float gy = M[12]*p0 + M[13]*p1 + M[14]*p2 + M[19];
    float gz = M[15]*p0 + M[16]*p1 + M[17]*p2 + M[20];
    const float cx = -51.0f - 0.2f, cy = -51.0f - 0.2f, cz = 0.0f - 10.0f;
    int ix = (int)((gx - cx) / 0.4f);
    int iy = (int)((gy - cy) / 0.4f);
    int iz = (int)((gz - cz) / 20.0f);
    bool kept = (ix >= 0) && (ix < 256) && (iy >= 0) && (iy < 256) && (iz == 0);
    int code = kept ? ((ix << 8) | iy) : -1;
    vcode[i] = code;

    int b = bn / 6;
    uint_t key = kept ? (uint_t)((b << 16) | code) : 0xFFFFFFFFu;
    uint_t prevkey = __shfl_up(key, 1);
    bool leader = (lane == 0) || (key != prevkey);
    unsigned long long mask = __ballot(leader);
    if (leader && kept) {
        unsigned long long higher = mask & ~((2ULL << lane) - 1ULL);
        int nxt = higher ? (__ffsll((long long)higher) - 1) : 64;
        atomicAdd(&cnt[key], (uint_t)(nxt - lane));
    }
}

// ---- cast + transpose img_feats fp32 [img][ci][px] -> bf16 [img*px][ci] ----
__global__ __launch_bounds__(256) void cast_transpose_kernel(
    const float* __restrict__ in, ushort_t* __restrict__ out)
{
    __shared__ __align__(16) ushort_t lds[64 * 264];
    int img = blockIdx.y;
    int px0 = blockIdx.x * 64;
    int t = threadIdx.x;
    const float* src = in + (size_t)img * NCH * NPIX;
    int pxl = t & 63;
    int cib = t >> 6;
    #pragma unroll 4
    for (int cc = 0; cc < 64; ++cc) {
        int ci = cc * 4 + cib;
        float v = src[(size_t)ci * NPIX + px0 + pxl];
        lds[pxl * 264 + ci] = f2bf(v);
    }
    __syncthreads();
    int wv = t >> 6, lane = t & 63;
    uint2* outv = (uint2*)out;
    #pragma unroll
    for (int i = 0; i < 16; ++i) {
        int p = wv * 16 + i;
        uint2 val = *(const uint2*)&lds[p * 264 + lane * 4];
        outv[(size_t)(img * NPIX + px0 + p) * 64 + lane] = val;
    }
}

// ---- 3x3 conv + BN + ReLU via bf16 MFMA (round-6 proven config) ----
// grid (img*32 rows, 2 co-groups of 128), block 256 (4 waves), m=2 per wave.
// LDS 16B-chunk slot XOR-swizzled with (col>>1)&3 -> conflict-free reads.
__global__ __launch_bounds__(256, 3) void conv3x3_mfma(
    const ushort_t* __restrict__ in,     // [img*2816][256] bf16
    const ushort_t* __restrict__ wswz,   // [9][8][16][64][8] bf16 (single)
    const float* __restrict__ Abn, const float* __restrict__ Cbn,
    ushort_t* __restrict__ out)          // [img*2816][256] bf16
{
    __shared__ __align__(16) ushort_t lds[2][8640];
    int bx = blockIdx.x;            // img*32 + h
    int cg = blockIdx.y;
    int img = bx >> 5, h = bx & 31;
    int t = threadIdx.x;
    int w = t >> 6, l = t & 63;
    int q = l >> 4, c = l & 15;
    const int n0s[6] = {0, 16, 32, 48, 64, 72};

    // zero both buffers once (halo + out-of-range rows stay zero forever)
    for (int i = t; i < 8640; i += 256) ((uint_t*)lds)[i] = 0;

    const u32x4* src4 = (const u32x4*)(in + (size_t)img * NPIX * 256);
    const bf16x8* wsA = (const bf16x8*)wswz;

    // hoisted per-thread staging geometry (5 chunks of 16B per thread), swizzled slot
    int gbase[5], loff[5];
    bool sval[5];
    #pragma unroll
    for (int k = 0; k < 5; ++k) {
        int p = t + k * 256;
        bool valid = (p < 1056);
        int chunk = p >> 2, sub = p & 3;
        int r = chunk / 88;
        int col = chunk - r * 88;
        int hin = h - 1 + r;
        bool inb = valid && (hin >= 0) && (hin < FH);
        sval[k] = inb;
        gbase[k] = inb ? ((hin * 88 + col) * 32 + sub) : 0;
        int cs = col + 1;                         // stored column
        int slot = sub ^ ((cs >> 1) & 3);         // bank swizzle
        loff[k] = ((r * 90 + cs) * 4 + slot) * 8;
    }

    floatx4 acc[2][6];
    #pragma unroll
    for (int m = 0; m < 2; ++m)
        #pragma unroll
        for (int n = 0; n < 6; ++n)
            acc[m][n] = (floatx4){0.f, 0.f, 0.f, 0.f};

    int g0 = cg * 8 + w * 2;

    __syncthreads();                 // zeros visible
    #pragma unroll
    for (int k = 0; k < 5; ++k)
        if (sval[k]) *(u32x4*)&lds[0][loff[k]] = src4[gbase[k]];

    int buf = 0;
    for (int kb = 0; kb < 8; ++kb) {
        __syncthreads();
        u32x4 sreg[5];
        if (kb < 7) {
            #pragma unroll
            for (int k = 0; k < 5; ++k)
                if (sval[k]) sreg[k] = src4[gbase[k] + (kb + 1) * 4];
        }
        const bf16x8* B = (const bf16x8*)lds[buf];

        // A-fragment prefetch, one tap ahead (single bf16 weights)
        bf16x8 a0, a1;
        {
            int pa = (0 * 8 + kb) * 16;
            a0 = wsA[(size_t)(pa + g0    ) * 64 + l];
            a1 = wsA[(size_t)(pa + g0 + 1) * 64 + l];
        }
        #pragma unroll
        for (int t9 = 0; t9 < 9; ++t9) {
            bf16x8 na0, na1;
            if (t9 < 8) {
                int pa = ((t9 + 1) * 8 + kb) * 16;
                na0 = wsA[(size_t)(pa + g0    ) * 64 + l];
                na1 = wsA[(size_t)(pa + g0 + 1) * 64 + l];
            }
            int ky = t9 / 3, kx = t9 - ky * 3;
            #pragma unroll
            for (int n = 0; n < 6; ++n) {
                int col = n0s[n] + kx + c;        // stored column
                int slot = q ^ ((col >> 1) & 3);
                bf16x8 b = B[(ky * 90 + col) * 4 + slot];
                acc[0][n] = __builtin_amdgcn_mfma_f32_16x16x32_bf16(a0, b, acc[0][n], 0, 0, 0);
                acc[1][n] = __builtin_amdgcn_mfma_f32_16x16x32_bf16(a1, b, acc[1][n], 0, 0, 0);
            }
            if (t9 < 8) { a0 = na0; a1 = na1; }
        }
        if (kb < 7) {
            #pragma unroll
            for (int k = 0; k < 5; ++k)
                if (sval[k]) *(u32x4*)&lds[buf ^ 1][loff[k]] = sreg[k];
        }
        buf ^= 1;
    }

    // epilogue: BN + ReLU, store bf16 channel-last
    #pragma unroll
    for (int m = 0; m < 2; ++m) {
        int cob = cg * 128 + w * 32 + m * 16 + q * 4;
        float ba0 = Abn[cob+0], ba1 = Abn[cob+1], ba2 = Abn[cob+2], ba3 = Abn[cob+3];
        float bc0 = Cbn[cob+0], bc1 = Cbn[cob+1], bc2 = Cbn[cob+2], bc3 = Cbn[cob+3];
        #pragma unroll
        for (int n = 0; n < 6; ++n) {
            if (n == 5 && c < 8) continue;
            int col = n0s[n] + c;
            floatx4 v = acc[m][n];
            uint_t lo = (uint_t)f2bf(fmaxf(v[0]*ba0+bc0, 0.f)) | ((uint_t)f2bf(fmaxf(v[1]*ba1+bc1, 0.f)) << 16);
            uint_t hi = (uint_t)f2bf(fmaxf(v[2]*ba2+bc2, 0.f)) | ((uint_t)f2bf(fmaxf(v[3]*ba3+bc3, 0.f)) << 16);
            uint2 val; val.x = lo; val.y = hi;
            *(uint2*)&out[((size_t)img * NPIX + h * 88 + col) * 256 + cob] = val;
        }
    }
}

// ---- 1x1 conv 256->130 via MFMA (split-bf16 weights) + fused gaussian weights ----
__global__ __launch_bounds__(256, 4) void gemm1x1_mfma(
    const ushort_t* __restrict__ act2,
    const ushort_t* __restrict__ wswz3,
    const float* __restrict__ b3,
    ushort_t* __restrict__ feat, float* __restrict__ wt)
{
    int t = threadIdx.x, wv = t >> 6, l = t & 63, q = l >> 4, c = l & 15;
    int n0 = (blockIdx.x * 4 + wv) * 16;
    int px = n0 + c;
    const bf16x8* A = (const bf16x8*)wswz3;
    const bf16x8* B = (const bf16x8*)act2;
    floatx4 acc[9];
    #pragma unroll
    for (int g = 0; g < 9; ++g) acc[g] = (floatx4){0.f, 0.f, 0.f, 0.f};
    for (int kb = 0; kb < 8; ++kb) {
        bf16x8 b = B[(size_t)px * 32 + kb * 4 + q];
        #pragma unroll
        for (int g = 0; g < 9; ++g) {
            size_t pa = (size_t)(kb * 9 + g) * 128;
            acc[g] = __builtin_amdgcn_mfma_f32_16x16x32_bf16(A[pa + l],      b, acc[g], 0, 0, 0);
            acc[g] = __builtin_amdgcn_mfma_f32_16x16x32_bf16(A[pa + 64 + l], b, acc[g], 0, 0, 0);
        }
    }
    // feat store (co 2..129)
    #pragma unroll
    for (int g = 0; g < 9; ++g) {
        #pragma unroll
        for (int r = 0; r < 4; ++r) {
            int co = g * 16 + q * 4 + r;
            if (co < 2 || co >= 130) continue;
            feat[(size_t)px * 128 + (co - 2)] = f2bf(acc[g][r] + b3[co]);
        }
    }
    // fused gaussian depth weights: mu=co0, log_sigma=co1 live on lanes 0..15
    float muv = acc[0][0] + b3[0];
    float lsv = acc[0][1] + b3[1];
    float mu_b  = __shfl(muv, c);               // broadcast from lane c (q==0)
    float sig   = expf(__shfl(lsv, c)) + 1e-6f;
    float ninv2 = -0.5f / (sig * sig);
    float g5[5]; float s = 0.0f;
    #pragma unroll
    for (int j = 0; j < 5; ++j) {
        float dv = 1.0f + 3.0f * (float)(q * 5 + j);
        float df = dv - mu_b;
        g5[j] = expf(df * df * ninv2);
        s += g5[j];
    }
    s += __shfl_xor(s, 16);
    s += __shfl_xor(s, 32);
    float inv = 1.0f / (s + 1e-6f);
    #pragma unroll
    for (int j = 0; j < 5; ++j)
        wt[(size_t)px * NDEP + q * 5 + j] = g5[j] * inv;
}

// ---- block-level exclusive scan (spine holds raw block sums) ----
__global__ __launch_bounds__(256) void scan_block_kernel(
    const uint_t* __restrict__ cnt, uint_t* __restrict__ offs, uint_t* __restrict__ spine)
{
    __shared__ uint_t s[256];
    int t = threadIdx.x;
    int i = blockIdx.x * 256 + t;
    uint_t v = cnt[i];
    s[t] = v;
    __syncthreads();
    #pragma unroll
    for (int off = 1; off < 256; off <<= 1) {
        uint_t add = (t >= off) ? s[t - off] : 0u;
        __syncthreads();
        s[t] += add;
        __syncthreads();
    }
    offs[i] = s[t] - v;
    if (t == 255) spine[blockIdx.x] = s[255];
}

// ---- fixup: per-block spine prefix (recomputed), offsets, cursor, mask, total ----
__global__ __launch_bounds__(256) void fixup_kernel(
    uint_t* __restrict__ offs, const uint_t* __restrict__ spine,
    uint_t* __restrict__ cursor, const uint_t* __restrict__ cnt,
    float* __restrict__ mask_out, uint_t* __restrict__ total)
{
    __shared__ uint_t red[256];
    int bid = blockIdx.x, t = threadIdx.x;
    uint_t part = 0;
    for (int j = t; j < bid; j += 256) part += spine[j];
    red[t] = part;
    __syncthreads();
    #pragma unroll
    for (int off = 128; off > 0; off >>= 1) {
        if (t < off) red[t] += red[t + off];
        __syncthreads();
    }
    uint_t prefix = red[0];
    int i = bid * 256 + t;
    uint_t o = offs[i] + prefix;
    offs[i] = o;
    cursor[i] = o;
    uint_t n = cnt[i];
    mask_out[i] = (n > 0) ? 1.0f : 0.0f;
    if (i == NKEY - 1) *total = o + n;
}

// ---- scatter with run-length aggregated cursor atomics ----
__global__ __launch_bounds__(256) void scatter_kernel(
    const int* __restrict__ vcode, const float* __restrict__ wt,
    uint_t* __restrict__ cursor, uint2* __restrict__ recs)
{
    int i = blockIdx.x * 256 + threadIdx.x;
    int lane = threadIdx.x & 63;
    int code = vcode[i];
    int hw  = i % NPIX;
    int tmp = i / NPIX;
    int d   = tmp % NDEP;
    int bn  = tmp / NDEP;
    int b   = bn / 6;
    int gp  = bn * NPIX + hw;           // < 33792, fits 16 bits
    bool active = (code >= 0);
    uint_t key = active ? (uint_t)((b << 16) | code) : 0xFFFFFFFFu;
    uint2 r;
    r.x = ((uint_t)(code & 0xffff) << 16) | (uint_t)gp;
    r.y = active ? __float_as_uint(wt[(size_t)gp * NDEP + d]) : 0u;

    uint_t prevkey = __shfl_up(key, 1);
    bool leader = (lane == 0) || (key != prevkey);
    unsigned long long mask = __ballot(leader);
    uint_t base = 0;
    if (leader && active) {
        unsigned long long higher = mask & ~((2ULL << lane) - 1ULL);
        int nxt = higher ? (__ffsll((long long)higher) - 1) : 64;
        base = atomicAdd(&cursor[key], (uint_t)(nxt - lane));
    }
    unsigned long long lower = mask & ((2ULL << lane) - 1ULL);
    int lead = 63 - __clzll((long long)lower);   // lower nonzero (lane0 is leader)
    base = __shfl(base, lead);
    if (active) recs[base + (lane - lead)] = r;
}

// ---- segmented reduce: one wave per 64-record chunk; feat is bf16 ----
__global__ __launch_bounds__(256) void segreduce_kernel(
    const uint2* __restrict__ recs, const uint_t* __restrict__ total,
    const uint_t* __restrict__ featu,   // [33792][64] dwords (bf16x2)
    float* __restrict__ bev_tmp)
{
    uint_t R = *total;
    int wid = blockIdx.x * 4 + (threadIdx.x >> 6);
    uint_t start = (uint_t)wid * 64u;
    if (start >= R) return;
    int lane = threadIdx.x & 63;
    uint_t ustart = __builtin_amdgcn_readfirstlane(start);

    uint2 r0 = recs[ustart];
    uint_t gp0 = r0.x & 0xffffu;
    uint_t prevk = ((gp0 >= 16896u) ? 0x10000u : 0u) | (r0.x >> 16);
    float acc0 = 0.f, acc1 = 0.f;

    #pragma unroll 8
    for (int e = 0; e < 64; ++e) {
        uint2 re = recs[ustart + e];
        uint_t gp = re.x & 0xffffu;
        uint_t key = ((gp >= 16896u) ? 0x10000u : 0u) | (re.x >> 16);
        float wv = __uint_as_float(re.y);
        if (ustart + e >= R) { key = prevk; wv = 0.f; gp = 0u; }  // uniform
        if (key != prevk) {                                        // uniform
            float* p = bev_tmp + (size_t)prevk * NOUTC;
            atomicAdd(p + 2 * lane,     acc0);
            atomicAdd(p + 2 * lane + 1, acc1);
            acc0 = acc1 = 0.f;
            prevk = key;
        }
        uint_t fv = featu[(size_t)gp * 64 + lane];
        acc0 = fmaf(wv, bf2f((ushort_t)(fv & 0xffffu)), acc0);
        acc1 = fmaf(wv, bf2f((ushort_t)(fv >> 16)),     acc1);
    }
    float* p = bev_tmp + (size_t)prevk * NOUTC;
    atomicAdd(p + 2 * lane,     acc0);
    atomicAdd(p + 2 * lane + 1, acc1);
}

// ---- channel-last -> channel-first BEV transpose ----
__global__ __launch_bounds__(256) void transpose_kernel(
    const float* __restrict__ bev_tmp, float* __restrict__ bev_out)
{
    __shared__ float lds[64 * 129];
    int blk = blockIdx.x;              // 0..2047
    int b   = blk >> 10;
    int v0  = (blk & 1023) * 64;
    int t   = threadIdx.x;
    const float* src = bev_tmp + ((size_t)b * NVOX + v0) * NOUTC;
    #pragma unroll
    for (int k = 0; k < 32; ++k) {
        int idx = k * 256 + t;
        int v = idx >> 7, ch = idx & 127;
        lds[v * 129 + ch] = src[idx];
    }
    __syncthreads();
    float* dst = bev_out + (size_t)b * NOUTC * NVOX + v0;
    #pragma unroll
    for (int k = 0; k < 32; ++k) {
        int idx = k * 256 + t;
        int vl = idx & 63, ch = idx >> 6;
        dst[(size_t)ch * NVOX + vl] = lds[vl * 129 + ch];
    }
}

extern "C" void kernel_launch(void* const* d_in, const int* in_sizes, int n_in,
                              void* d_out, int out_size, void* d_ws, size_t ws_size,
                              hipStream_t stream) {
    const float* c2e_rot    = (const float*)d_in[0];
    const float* c2e_trans  = (const float*)d_in[1];
    const float* intrins    = (const float*)d_in[2];
    const float* post_rot   = (const float*)d_in[3];
    const float* post_trans = (const float*)d_in[4];
    const float* img_feats  = (const float*)d_in[5];
    const float* conv1_w    = (const float*)d_in[6];
    const float* conv1_b    = (const float*)d_in[7];
    const float* bn1_s = (const float*)d_in[8];
    const float* bn1_b = (const float*)d_in[9];
    const float* bn1_m = (const float*)d_in[10];
    const float* bn1_v = (const float*)d_in[11];
    const float* conv2_w = (const float*)d_in[12];
    const float* conv2_b = (const float*)d_in[13];
    const float* bn2_s = (const float*)d_in[14];
    const float* bn2_b = (const float*)d_in[15];
    const float* bn2_m = (const float*)d_in[16];
    const float* bn2_v = (const float*)d_in[17];
    const float* conv3_w = (const float*)d_in[18];
    const float* conv3_b = (const float*)d_in[19];

    char* base = (char*)d_ws;
    float*    mats   = (float*)(base + B_MATS);
    float*    A1     = (float*)(base + B_A1);
    float*    C1     = (float*)(base + B_C1);
    float*    A2     = (float*)(base + B_A2);
    float*    C2     = (float*)(base + B_C2);
    uint_t*   total  = (uint_t*)(base + B_TOT);
    ushort_t* feat   = (ushort_t*)(base + B_FEAT);
    uint2*    recs   = (uint2*)(base + B_RECS);
    float*    bevtmp = (float*)(base + B_BEV);
    int*      vcode  = (int*)(base + B_VCODE);
    float*    wt     = (float*)(base + B_WT);
    uint_t*   cnt    = (uint_t*)(base + B_CNT);
    uint_t*   offs   = (uint_t*)(base + B_OFFS);
    uint_t*   cursor = (uint_t*)(base + B_CUR);
    uint_t*   spine  = (uint_t*)(base + B_SPINE);
    ushort_t* xbf    = (ushort_t*)(base + B_XBF);
    ushort_t* act1   = (ushort_t*)(base + B_ACT1);
    ushort_t* act2   = (ushort_t*)(base + B_ACT2);
    ushort_t* wswz1  = (ushort_t*)(base + B_WSWZ1);
    ushort_t* wswz2  = (ushort_t*)(base + B_WSWZ2);
    ushort_t* wswz3  = (ushort_t*)(base + B_WSWZ3);

    float* bev_out  = (float*)d_out;
    float* mask_out = bev_out + BEV_FLOATS;

    hipMemsetAsync(cnt, 0, NKEY * sizeof(uint_t), stream);
    wprep_all_kernel<<<4753, 256, 0, stream>>>(conv1_w, wswz1, conv2_w, wswz2, conv3_w, wswz3,
                                               c2e_rot, c2e_trans, intrins, post_rot, post_trans,
                                               conv1_b, bn1_s, bn1_b, bn1_m, bn1_v,
                                               conv2_b, bn2_s, bn2_b, bn2_m, bn2_v,
                                               mats, A1, C1, A2, C2);
    geom_kernel<<<NPTS / 256, 256, 0, stream>>>(mats, vcode, cnt);
    cast_transpose_kernel<<<dim3(44, 12), 256, 0, stream>>>(img_feats, xbf);
    conv3x3_mfma<<<dim3(NIMG * 32, 2), 256, 0, stream>>>(xbf,  wswz1, A1, C1, act1);
    conv3x3_mfma<<<dim3(NIMG * 32, 2), 256, 0, stream>>>(act1, wswz2, A2, C2, act2);
    gemm1x1_mfma<<<528, 256, 0, stream>>>(act2, wswz3, conv3_b, feat, wt);
    scan_block_kernel<<<NKEY / 256, 256, 0, stream>>>(cnt, offs, spine);
    fixup_kernel<<<NKEY / 256, 256, 0, stream>>>(offs, spine, cursor, cnt, mask_out, total);
    scatter_kernel<<<NPTS / 256, 256, 0, stream>>>(vcode, wt, cursor, recs);
    // all hole-resident buffers now dead
    hipMemsetAsync(bevtmp, 0, (size_t)BEV_FLOATS * sizeof(float), stream);
    segreduce_kernel<<<(NPTS / 64 + 3) / 4, 256, 0, stream>>>(recs, total, (const uint_t*)feat, bevtmp);
    transpose_kernel<<<2048, 256, 0, stream>>>(bevtmp, bev_out);
}